// Round 1
// baseline (86.204 us; speedup 1.0000x reference)
//
#include <hip/hip_runtime.h>

// ReflectionRayTracer: 8192 rays x 2048 quad surfaces. out[ray][surf] = t*mask.
//
// R7: split coeff-precompute kernel + 2-surfaces-per-thread packed-f32 sweep.
//  Theory: timed region = harness poison fill (~44.7us, fixed) + trace kernel
//  (~40us). Trace kernel is issue/latency-bound (VALU floor ~5us, write floor
//  ~11us), so attack issue-slot count per pair:
//   - coeff_kernel (8 blocks) computes the 13 per-surface coefficients once
//     into d_ws as SoA [13][2048] -> sweep threads reload them coalesced.
//     Removes the ~60-VALU+4-trans preamble from all 2048 sweep blocks.
//   - trace_kernel: each thread owns 2 adjacent surfaces held in float2 SoA.
//     All per-pair FMAs become v_pk_fma_f32 (2 f32 lanes/inst) => VALU issue
//     per pair ~halves. Store is global_store_dwordx2 (512B/wave contiguous)
//     => store insts + 64b addr arith per pair halve.
//   - RPB=16 keeps grid = (4,512) = 2048 blocks = 8 blocks/CU, 4 waves/block
//     => 8 waves/SIMD, occupancy identical to R6 (isolate the variable).
//  Per-pair math is formula- and contraction-identical to R6 => absmax should
//  remain exactly 2.578125.

#define N_RAYS 8192
#define N_SURF 2048
constexpr int RPB = 16;   // rays per block
constexpr int SPT = 2;    // surfaces per thread

typedef float v2f __attribute__((ext_vector_type(2)));
#define FMA2(a, b, c) __builtin_elementwise_fma((a), (b), (c))

__device__ __forceinline__ float safef(float x) {
    return (x == 0.0f) ? 1e-18f : x;   // jnp.where(x==0, EPS, x)
}

// ---- kernel 1: per-surface coefficients, SoA cf[13][N_SURF] ----
__global__ __launch_bounds__(256) void coeff_kernel(
    const float* __restrict__ V, float* __restrict__ cf)
{
    const int s = blockIdx.x * 256 + threadIdx.x;

    const float4 p0 = *(const float4*)(V + (size_t)s * 12);
    const float4 p1 = *(const float4*)(V + (size_t)s * 12 + 4);
    const float4 p2 = *(const float4*)(V + (size_t)s * 12 + 8);
    const float ax = p0.x, ay = p0.y, az = p0.z;       // a = V[s][0]
    const float bx = p0.w, by = p1.x, bz = p1.y;       // b = V[s][1]
    const float cx = p1.z, cy = p1.w, cz = p2.x;       // c = V[s][2]
    const float wx = p2.y, wy = p2.z, wz = p2.w;       // V[s][3]

    // Plane: v = normalize(cross(b-a, c-a)); k = -dot(v, V[s][3])
    const float e0x = bx - ax, e0y = by - ay, e0z = bz - az;
    const float e1x = cx - ax, e1y = cy - ay, e1z = cz - az;
    const float nx = e0y * e1z - e0z * e1y;
    const float ny = e0z * e1x - e0x * e1z;
    const float nz = e0x * e1y - e0y * e1x;
    const float rn = __builtin_amdgcn_rsqf(fmaf(nx, nx, fmaf(ny, ny, nz * nz)));
    const float vx = nx * rn, vy = ny * rn, vz = nz * rn;
    const float k = -fmaf(vx, wx, fmaf(vy, wy, vz * wz));

    const float B  = ax * bz - az * bx;
    const float D  = ax * by - ay * bx;                 // G == D
    const float E  = ax * cz - az * cx;
    const float P  = ay * cx - ax * cy;
    const float F  = B * P;
    const float rden = __builtin_amdgcn_rcpf(safef(D * fmaf(E, D, F)));
    const float rD   = __builtin_amdgcn_rcpf(safef(D));
    const float rAX  = __builtin_amdgcn_rcpf(safef(ax));

    const float DB = D * B, DD = D * D;
    const float g0 = (DB * ay - DD * az) * rden;
    const float g1 = -(DB * ax) * rden;
    const float g2 = (DD * ax) * rden;
    const float bp  = P * rD;
    const float bb0 = fmaf(bp, g0, -ay * rD);
    const float bb1 = fmaf(bp, g1,  ax * rD);
    const float bb2 = bp * g2;
    const float ab = -bx * rAX, ac = -cx * rAX;
    const float aa0 = fmaf(ab, bb0, fmaf(ac, g0, rAX));
    const float aa1 = fmaf(ab, bb1, ac * g1);
    const float aa2 = fmaf(ab, bb2, ac * g2);

    cf[ 0 * N_SURF + s] = vx;
    cf[ 1 * N_SURF + s] = vy;
    cf[ 2 * N_SURF + s] = vz;
    cf[ 3 * N_SURF + s] = k;
    cf[ 4 * N_SURF + s] = g0;
    cf[ 5 * N_SURF + s] = g1;
    cf[ 6 * N_SURF + s] = g2;
    cf[ 7 * N_SURF + s] = bb0;
    cf[ 8 * N_SURF + s] = bb1;
    cf[ 9 * N_SURF + s] = bb2;
    cf[10 * N_SURF + s] = aa0;
    cf[11 * N_SURF + s] = aa1;
    cf[12 * N_SURF + s] = aa2;
}

// ---- kernel 2: the ray x surface sweep, 2 surfaces/thread packed ----
__global__ __launch_bounds__(256, 8) void trace_kernel(
    const float* __restrict__ o, const float* __restrict__ dr,
    const float* __restrict__ cf, float* __restrict__ out)
{
    const int s0 = (blockIdx.x * 256 + threadIdx.x) * SPT;  // surface pair base

    const v2f vx  = *(const v2f*)(cf +  0 * N_SURF + s0);
    const v2f vy  = *(const v2f*)(cf +  1 * N_SURF + s0);
    const v2f vz  = *(const v2f*)(cf +  2 * N_SURF + s0);
    const v2f kk  = *(const v2f*)(cf +  3 * N_SURF + s0);
    const v2f g0  = *(const v2f*)(cf +  4 * N_SURF + s0);
    const v2f g1  = *(const v2f*)(cf +  5 * N_SURF + s0);
    const v2f g2  = *(const v2f*)(cf +  6 * N_SURF + s0);
    const v2f bb0 = *(const v2f*)(cf +  7 * N_SURF + s0);
    const v2f bb1 = *(const v2f*)(cf +  8 * N_SURF + s0);
    const v2f bb2 = *(const v2f*)(cf +  9 * N_SURF + s0);
    const v2f aa0 = *(const v2f*)(cf + 10 * N_SURF + s0);
    const v2f aa1 = *(const v2f*)(cf + 11 * N_SURF + s0);
    const v2f aa2 = *(const v2f*)(cf + 12 * N_SURF + s0);

    const int ray0 = blockIdx.y * RPB;
    float* outp = out + (size_t)ray0 * N_SURF + s0;

#pragma unroll 4
    for (int i = 0; i < RPB; ++i) {
        const int ray = ray0 + i;
        // Wave-uniform ray loads -> scalar (SMEM) loads.
        const float o0 = o[ray * 3 + 0], o1 = o[ray * 3 + 1], o2 = o[ray * 3 + 2];
        const float d0 = dr[ray * 3 + 0], d1 = dr[ray * 3 + 1], d2 = dr[ray * 3 + 2];
        const v2f o0v = o0, o1v = o1, o2v = o2;
        const v2f d0v = d0, d1v = d1, d2v = d2;

        const v2f vo_k = FMA2(o0v, vx, FMA2(o1v, vy, FMA2(o2v, vz, kk))); // k + v.o
        const v2f vd   = FMA2(d0v, vx, FMA2(d1v, vy, d2v * vz));
        v2f rv;
        rv.x = __builtin_amdgcn_rcpf(vd.x);
        rv.y = __builtin_amdgcn_rcpf(vd.y);
        const v2f t = -vo_k * rv;

        const v2f rx = FMA2(t, d0v, o0v);
        const v2f ry = FMA2(t, d1v, o1v);
        const v2f rz = FMA2(t, d2v, o2v);

        const v2f gam = FMA2(g0,  rx, FMA2(g1,  ry, g2  * rz));
        const v2f bet = FMA2(bb0, rx, FMA2(bb1, ry, bb2 * rz));
        const v2f alp = FMA2(aa0, rx, FMA2(aa1, ry, aa2 * rz));

        const float mnx = fminf(fminf(bet.x, gam.x), alp.x);  // v_min3_f32
        const float mny = fminf(fminf(bet.y, gam.y), alp.y);
        v2f res;
        res.x = (mnx > 0.0f) ? t.x : 0.0f;
        res.y = (mny > 0.0f) ? t.y : 0.0f;
        *(v2f*)(outp + (size_t)i * N_SURF) = res;   // global_store_dwordx2, 512B/wave
    }
}

extern "C" void kernel_launch(void* const* d_in, const int* in_sizes, int n_in,
                              void* d_out, int out_size, void* d_ws, size_t ws_size,
                              hipStream_t stream) {
    const float* o  = (const float*)d_in[0];
    const float* dr = (const float*)d_in[1];
    const float* V  = (const float*)d_in[2];
    float* out = (float*)d_out;
    float* cf  = (float*)d_ws;   // 13 * 2048 * 4 B = 106 KiB

    coeff_kernel<<<dim3(N_SURF / 256), dim3(256), 0, stream>>>(V, cf);
    trace_kernel<<<dim3(N_SURF / (256 * SPT), N_RAYS / RPB), dim3(256), 0, stream>>>(o, dr, cf, out);
}